// Round 1
// baseline (569.458 us; speedup 1.0000x reference)
//
#include <hip/hip_runtime.h>
#include <math.h>

// Problem constants (fixed by reference setup_inputs): pred [32,1,512,512] f32
#define IMG_W 512
#define IMG_H 512
#define HW (IMG_W * IMG_H)      // 262144 = 2^18
#define LOGHW 18
#define NIMG 32
#define NTOT (NIMG * HW)        // 8388608
#define NCHUNK (NTOT / 1024)    // 8192 chunks of 1024 px; 256 chunks per image

// ---------------- K1: init labels (min-index UF), zero stats ----------------
__global__ void k_init(const float* __restrict__ pred, int* __restrict__ L,
                       unsigned long long* __restrict__ stats,
                       double* __restrict__ accum) {
    int gid = blockIdx.x * blockDim.x + threadIdx.x;
    if (gid < NTOT) {
        int local = gid & (HW - 1);
        L[gid] = (pred[gid] >= 0.5f) ? local : -1;
    }
    if (gid < NIMG) stats[gid] = 0ULL;
    if (gid == 0) *accum = 0.0;
}

// ---------------- K2: union-find merge (atomicMin, lock-free) ---------------
__device__ __forceinline__ int find_root(const volatile int* L, int x) {
    int p = L[x];
    while (p != x) { x = p; p = L[x]; }
    return x;
}

__device__ __forceinline__ void unite(int* L, int a, int b) {
    while (true) {
        a = find_root((const volatile int*)L, a);
        b = find_root((const volatile int*)L, b);
        if (a == b) return;
        if (a < b) { int t = a; a = b; b = t; }  // ensure a > b
        int old = atomicMin(&L[a], b);
        if (old == a) return;   // linked a -> b
        a = old;                // a already had a smaller parent; merge that
    }
}

__global__ void k_merge(int* __restrict__ L) {
    int gid = blockIdx.x * blockDim.x + threadIdx.x;
    if (gid >= NTOT) return;
    int img = gid >> LOGHW;
    int local = gid & (HW - 1);
    int* Li = L + (img << LOGHW);
    if (Li[local] < 0) return;                 // background
    int x = local & (IMG_W - 1);
    if (x + 1 < IMG_W && Li[local + 1] >= 0)      unite(Li, local, local + 1);
    if (local + IMG_W < HW && Li[local + IMG_W] >= 0) unite(Li, local, local + IMG_W);
}

// ---------------- K3: flatten to roots --------------------------------------
__global__ void k_flatten(int* __restrict__ L) {
    int gid = blockIdx.x * blockDim.x + threadIdx.x;
    if (gid >= NTOT) return;
    int img = gid >> LOGHW;
    int local = gid & (HW - 1);
    int* Li = L + (img << LOGHW);
    int p = Li[local];
    if (p < 0) return;
    int x = local;
    while (p != x) { x = p; p = Li[x]; }
    Li[local] = x;
}

// ---------------- K4a: per-chunk root counts --------------------------------
__global__ void k_blocksum(const int* __restrict__ L, int* __restrict__ blockSums) {
    __shared__ int sdata[256];
    int base = blockIdx.x * 1024;
    int cnt = 0;
#pragma unroll
    for (int k = 0; k < 4; k++) {
        int g = base + threadIdx.x + k * 256;
        int local = g & (HW - 1);
        cnt += (L[g] == local) ? 1 : 0;
    }
    sdata[threadIdx.x] = cnt;
    __syncthreads();
    for (int s = 128; s > 0; s >>= 1) {
        if (threadIdx.x < s) sdata[threadIdx.x] += sdata[threadIdx.x + s];
        __syncthreads();
    }
    if (threadIdx.x == 0) blockSums[blockIdx.x] = sdata[0];
}

// ---------------- K4b: per-image exclusive scan of 256 chunk sums -----------
__global__ void k_scanblocks(const int* __restrict__ blockSums,
                             int* __restrict__ blockOffs) {
    __shared__ int s[256];
    int img = blockIdx.x;
    int t = threadIdx.x;
    int val = blockSums[img * 256 + t];
    s[t] = val;
    __syncthreads();
    for (int off = 1; off < 256; off <<= 1) {
        int v2 = (t >= off) ? s[t - off] : 0;
        __syncthreads();
        s[t] += v2;
        __syncthreads();
    }
    blockOffs[img * 256 + t] = s[t] - val;   // exclusive
}

// ---------------- K4c: inclusive root-prefix P[i] ---------------------------
__global__ void k_writeP(const int* __restrict__ L, const int* __restrict__ blockOffs,
                         int* __restrict__ P) {
    __shared__ int s[256];
    int base = blockIdx.x * 1024;
    int t = threadIdx.x;
    int f[4];
    int sum = 0;
#pragma unroll
    for (int k = 0; k < 4; k++) {
        int g = base + t * 4 + k;
        int local = g & (HW - 1);
        f[k] = (L[g] == local) ? 1 : 0;
        sum += f[k];
    }
    s[t] = sum;
    __syncthreads();
    for (int off = 1; off < 256; off <<= 1) {
        int v2 = (t >= off) ? s[t - off] : 0;
        __syncthreads();
        s[t] += v2;
        __syncthreads();
    }
    int run = (s[t] - sum) + blockOffs[blockIdx.x];
#pragma unroll
    for (int k = 0; k < 4; k++) {
        run += f[k];
        P[base + t * 4 + k] = run;   // inclusive prefix of root flags
    }
}

// ---------------- K5: per-image argmax of labels.flat[1:] -------------------
// key = (label << 32) | (HW - i): max label first, then min index on ties.
__global__ void k_argmax(const int* __restrict__ L, const int* __restrict__ P,
                         unsigned long long* __restrict__ stats) {
    __shared__ unsigned long long s[256];
    int base = blockIdx.x * 1024;
    int img = blockIdx.x >> 8;   // 256 chunks per image
    const int* Pi = P + (img << LOGHW);
    unsigned long long best = 0ULL;
#pragma unroll
    for (int k = 0; k < 4; k++) {
        int g = base + threadIdx.x + k * 256;
        int local = g & (HW - 1);
        if (local == 0) continue;          // argmax runs over flat[1:]
        int r = L[g];
        unsigned long long lf = (r >= 0) ? (unsigned long long)Pi[r] : 0ULL;
        unsigned long long key = (lf << 32) | (unsigned long long)(HW - local);
        if (key > best) best = key;
    }
    s[threadIdx.x] = best;
    __syncthreads();
    for (int st = 128; st > 0; st >>= 1) {
        if (threadIdx.x < st && s[threadIdx.x + st] > s[threadIdx.x])
            s[threadIdx.x] = s[threadIdx.x + st];
        __syncthreads();
    }
    if (threadIdx.x == 0) atomicMax(&stats[img], s[0]);
}

// ---------------- K6: fused target + clamped BCE reduce ---------------------
__global__ void k_loss(const float* __restrict__ pred, const int* __restrict__ L,
                       const int* __restrict__ P,
                       const unsigned long long* __restrict__ stats,
                       double* __restrict__ accum) {
    __shared__ float s[256];
    int base = blockIdx.x * 1024;
    int img = blockIdx.x >> 8;
    unsigned long long key = stats[img];
    int v = HW - (int)(key & 0xffffffffULL);   // = argmax(lf[1:]) + 1
    const int* Pi = P + (img << LOGHW);
    float acc = 0.0f;
#pragma unroll
    for (int k = 0; k < 4; k++) {
        int g = base + threadIdx.x + k * 256;
        float p = pred[g];
        float logp = fmaxf(logf(p), -100.0f);
        float log1mp = fmaxf(log1pf(-p), -100.0f);
        int r = L[g];
        int lf = (r >= 0) ? Pi[r] : 0;         // label value; v >= 1 so bg never hits
        acc += (lf == v) ? logp : log1mp;
    }
    s[threadIdx.x] = acc;
    __syncthreads();
    for (int st = 128; st > 0; st >>= 1) {
        if (threadIdx.x < st) s[threadIdx.x] += s[threadIdx.x + st];
        __syncthreads();
    }
    if (threadIdx.x == 0) atomicAdd(accum, (double)s[0]);
}

// ---------------- K7: finalize ----------------------------------------------
__global__ void k_final(const double* __restrict__ accum, float* __restrict__ out) {
    out[0] = (float)(-(*accum) / (double)NTOT);
}

extern "C" void kernel_launch(void* const* d_in, const int* in_sizes, int n_in,
                              void* d_out, int out_size, void* d_ws, size_t ws_size,
                              hipStream_t stream) {
    const float* pred = (const float*)d_in[0];
    float* out = (float*)d_out;

    char* ws = (char*)d_ws;
    int* L = (int*)ws;                                       // 33.5 MB
    int* P = (int*)(ws + (size_t)NTOT * 4);                  // 33.5 MB
    int* blockSums = (int*)(ws + (size_t)NTOT * 8);          // 32 KB
    int* blockOffs = blockSums + NCHUNK;                     // 32 KB
    unsigned long long* stats =
        (unsigned long long*)(ws + (size_t)NTOT * 8 + (size_t)NCHUNK * 8);
    double* accum = (double*)(stats + NIMG);

    dim3 b(256);
    k_init<<<dim3(NTOT / 256), b, 0, stream>>>(pred, L, stats, accum);
    k_merge<<<dim3(NTOT / 256), b, 0, stream>>>(L);
    k_flatten<<<dim3(NTOT / 256), b, 0, stream>>>(L);
    k_blocksum<<<dim3(NCHUNK), b, 0, stream>>>(L, blockSums);
    k_scanblocks<<<dim3(NIMG), b, 0, stream>>>(blockSums, blockOffs);
    k_writeP<<<dim3(NCHUNK), b, 0, stream>>>(L, blockOffs, P);
    k_argmax<<<dim3(NCHUNK), b, 0, stream>>>(L, P, stats);
    k_loss<<<dim3(NCHUNK), b, 0, stream>>>(pred, L, P, stats, accum);
    k_final<<<1, 1, 0, stream>>>(accum, out);
}

// Round 2
// 437.907 us; speedup vs baseline: 1.3004x; 1.3004x over previous
//
#include <hip/hip_runtime.h>
#include <math.h>

// Problem constants (fixed by reference setup_inputs): pred [32,1,512,512] f32
#define IMG_W 512
#define IMG_H 512
#define HW (IMG_W * IMG_H)      // 262144 = 2^18
#define LOGHW 18
#define NIMG 32
#define NTOT (NIMG * HW)        // 8388608
#define NCHUNK (NTOT / 1024)    // 8192 chunks of 1024 px; 256 per image
#define TILE 64
#define TILES_X (IMG_W / TILE)  // 8
#define TILES_Y (IMG_H / TILE)  // 8
#define TPI (TILES_X * TILES_Y) // 64 tiles per image
#define NTILE (NIMG * TPI)      // 2048
#define VBORD ((TILES_X - 1) * IMG_H)          // 3584 vertical-border pairs/img
#define BORD_PER_IMG (VBORD + (TILES_Y - 1) * IMG_W)  // 7168
#define NBORD (NIMG * BORD_PER_IMG)            // 229376

// ---------------- lock-free min-index union-find ----------------------------
__device__ __forceinline__ int uf_find(const volatile int* L, int x) {
    int p = L[x];
    while (p != x) { x = p; p = L[x]; }
    return x;
}

__device__ __forceinline__ void uf_unite(int* L, int a, int b) {
    while (true) {
        a = uf_find((const volatile int*)L, a);
        b = uf_find((const volatile int*)L, b);
        if (a == b) return;
        if (a < b) { int t = a; a = b; b = t; }  // a > b
        int old = atomicMin(&L[a], b);
        if (old == a) return;
        a = old;
    }
}

// ---------------- K1: fused init + tile-local CCL in LDS --------------------
// One block per 64x64 tile. Local raster order == global raster order within
// a tile, so the LDS union-find's min-local-index root is the min-global-index
// pixel of each tile-portion — exactly what the global UF representation needs.
__global__ __launch_bounds__(256) void k_local(const float* __restrict__ pred,
                                               int* __restrict__ L,
                                               unsigned long long* __restrict__ stats,
                                               unsigned int* __restrict__ counter,
                                               double* __restrict__ accum) {
    __shared__ int lab[TILE * TILE];   // 16 KB
    int tile = blockIdx.x;
    int img = tile >> 6;               // / TPI
    int t = tile & (TPI - 1);
    int ty = t >> 3, tx = t & 7;
    int baseLocal = (ty * TILE) * IMG_W + tx * TILE;  // image-local origin
    const float* pi = pred + ((size_t)img << LOGHW);
    int* Li = L + ((size_t)img << LOGHW);
    int tid = threadIdx.x;

    // load (float4) + init labels
#pragma unroll
    for (int j = 0; j < 4; j++) {
        int i = (tid + j * 256) * 4;              // tile-flat index of 4-pack
        int ly = i >> 6, lx = i & 63;
        const float4 p4 = *(const float4*)(pi + baseLocal + ly * IMG_W + lx);
        lab[i + 0] = (p4.x >= 0.5f) ? i + 0 : -1;
        lab[i + 1] = (p4.y >= 0.5f) ? i + 1 : -1;
        lab[i + 2] = (p4.z >= 0.5f) ? i + 2 : -1;
        lab[i + 3] = (p4.w >= 0.5f) ? i + 3 : -1;
    }
    __syncthreads();
    // local unites (right + down, intra-tile only)
#pragma unroll
    for (int k = 0; k < 16; k++) {
        int i = tid + k * 256;
        if (lab[i] < 0) continue;
        int lx = i & 63;
        if (lx < 63 && lab[i + 1] >= 0) uf_unite(lab, i, i + 1);
        if (i < TILE * TILE - TILE && lab[i + TILE] >= 0) uf_unite(lab, i, i + TILE);
    }
    __syncthreads();
    // flatten + write global parent pointers (int4)
#pragma unroll
    for (int j = 0; j < 4; j++) {
        int i = (tid + j * 256) * 4;
        int ly = i >> 6, lx = i & 63;
        int4 o;
        int* op = (int*)&o;
#pragma unroll
        for (int k = 0; k < 4; k++) {
            int p = lab[i + k];
            if (p < 0) op[k] = -1;
            else {
                int x = i + k;
                while (p != x) { x = p; p = lab[x]; }
                op[k] = baseLocal + (x >> 6) * IMG_W + (x & 63);
            }
        }
        *(int4*)(Li + baseLocal + ly * IMG_W + lx) = o;
    }
    if (blockIdx.x == 0) {
        if (tid < NIMG) stats[tid] = 0ULL;
        if (tid == 0) { *counter = 0u; *accum = 0.0; }
    }
}

// ---------------- K2: cross-tile border unites ------------------------------
__global__ void k_border(int* __restrict__ L) {
    int gid = blockIdx.x * blockDim.x + threadIdx.x;
    if (gid >= NBORD) return;
    int img = gid / BORD_PER_IMG;
    int r = gid - img * BORD_PER_IMG;
    int* Li = L + ((size_t)img << LOGHW);
    int a, b;
    if (r < VBORD) {
        int k = r >> 9, y = r & 511;           // r / 512, r % 512
        int x = k * TILE + (TILE - 1);
        a = y * IMG_W + x; b = a + 1;
    } else {
        int r2 = r - VBORD;
        int k = r2 >> 9, x = r2 & 511;
        int y = k * TILE + (TILE - 1);
        a = y * IMG_W + x; b = a + IMG_W;
    }
    if (Li[a] >= 0 && Li[b] >= 0) uf_unite(Li, a, b);
}

// ---------------- K3: flatten to roots + per-chunk root counts --------------
__global__ __launch_bounds__(256) void k_flatten(int* __restrict__ L,
                                                 int* __restrict__ blockSums) {
    __shared__ int sdata[256];
    int base = blockIdx.x * 1024;
    int img = base >> LOGHW;                   // chunks never straddle images
    int* Li = L + ((size_t)img << LOGHW);
    int cnt = 0;
#pragma unroll
    for (int k = 0; k < 4; k++) {
        int g = base + threadIdx.x + k * 256;
        int local = g & (HW - 1);
        int p = Li[local];
        if (p >= 0) {
            int x = local;
            while (p != x) { x = p; p = Li[x]; }
            Li[local] = x;
            cnt += (x == local) ? 1 : 0;
        }
    }
    sdata[threadIdx.x] = cnt;
    __syncthreads();
    for (int s = 128; s > 0; s >>= 1) {
        if (threadIdx.x < s) sdata[threadIdx.x] += sdata[threadIdx.x + s];
        __syncthreads();
    }
    if (threadIdx.x == 0) blockSums[blockIdx.x] = sdata[0];
}

// ---------------- K4: per-image exclusive scan of 256 chunk sums ------------
__global__ void k_scan(const int* __restrict__ blockSums, int* __restrict__ blockOffs) {
    __shared__ int s[256];
    int img = blockIdx.x;
    int t = threadIdx.x;
    int val = blockSums[img * 256 + t];
    s[t] = val;
    __syncthreads();
    for (int off = 1; off < 256; off <<= 1) {
        int v2 = (t >= off) ? s[t - off] : 0;
        __syncthreads();
        s[t] += v2;
        __syncthreads();
    }
    blockOffs[img * 256 + t] = s[t] - val;   // exclusive
}

// ---------------- K5: write inclusive root-prefix P + fused argmax ----------
// Only two pixel classes can win argmax(lf[1:]): a root pixel (first pixel of
// its component, label known in-register), or a pixel whose root is 0 (the
// zero-rooted component has label 1; its first index>=1 pixel is the candidate
// when pixel 0 is a root). Everything else is dominated by its own root's key.
__global__ __launch_bounds__(256) void k_labels(const int* __restrict__ L,
                                                const int* __restrict__ blockOffs,
                                                int* __restrict__ P,
                                                unsigned long long* __restrict__ stats) {
    __shared__ int s[256];
    __shared__ unsigned long long smax[256];
    int base = blockIdx.x * 1024;
    int img = base >> LOGHW;
    int t = threadIdx.x;
    int4 l4 = *(const int4*)(L + base + t * 4);
    const int* Lg = (const int*)&l4;
    int f[4];
    int sum = 0;
#pragma unroll
    for (int k = 0; k < 4; k++) {
        int local = (base + t * 4 + k) & (HW - 1);
        f[k] = (Lg[k] == local) ? 1 : 0;
        sum += f[k];
    }
    s[t] = sum;
    __syncthreads();
    for (int off = 1; off < 256; off <<= 1) {
        int v2 = (t >= off) ? s[t - off] : 0;
        __syncthreads();
        s[t] += v2;
        __syncthreads();
    }
    int run = (s[t] - sum) + blockOffs[blockIdx.x];
    unsigned long long best = 0ULL;
    int4 p4;
    int* pp = (int*)&p4;
#pragma unroll
    for (int k = 0; k < 4; k++) {
        int local = (base + t * 4 + k) & (HW - 1);
        run += f[k];
        pp[k] = run;
        if (local >= 1) {
            if (f[k]) {
                unsigned long long key =
                    ((unsigned long long)run << 32) | (unsigned)(HW - local);
                if (key > best) best = key;
            }
            if (Lg[k] == 0) {
                unsigned long long key = (1ULL << 32) | (unsigned)(HW - local);
                if (key > best) best = key;
            }
        }
    }
    *(int4*)(P + base + t * 4) = p4;
    smax[t] = best;
    __syncthreads();
    for (int st = 128; st > 0; st >>= 1) {
        if (t < st && smax[t + st] > smax[t]) smax[t] = smax[t + st];
        __syncthreads();
    }
    if (t == 0 && smax[0]) atomicMax(&stats[img], smax[0]);
}

// ---------------- K6: fused target + clamped BCE + finalize -----------------
__global__ __launch_bounds__(256) void k_loss(const float* __restrict__ pred,
                                              const int* __restrict__ L,
                                              const int* __restrict__ P,
                                              const unsigned long long* __restrict__ stats,
                                              double* __restrict__ accum,
                                              unsigned int* __restrict__ counter,
                                              float* __restrict__ out) {
    __shared__ float s[256];
    __shared__ int s_rv;
    __shared__ bool isLast;
    int base = blockIdx.x * 1024;
    int img = base >> LOGHW;
    int t = threadIdx.x;
    if (t == 0) {
        unsigned long long key = stats[img];
        int v = HW - (int)(key & 0xffffffffULL);  // = argmax(lf[1:]) + 1
        const int* Pi = P + ((size_t)img << LOGHW);
        int rv = -2;   // sentinel: never equals any root (-1 = background)
        if (v >= 1 && Pi[HW - 1] >= v) {
            int lo = 0, hi = HW - 1;
            while (lo < hi) {                    // smallest j with Pi[j] >= v
                int mid = (lo + hi) >> 1;
                if (Pi[mid] >= v) hi = mid; else lo = mid + 1;
            }
            if (Pi[lo] == v && L[((size_t)img << LOGHW) + lo] == lo) rv = lo;
        }
        s_rv = rv;
    }
    __syncthreads();
    int rv = s_rv;
    float4 pr4 = *(const float4*)(pred + base + t * 4);
    int4 l4 = *(const int4*)(L + base + t * 4);
    const float* pr = (const float*)&pr4;
    const int* Lg = (const int*)&l4;
    float acc = 0.0f;
#pragma unroll
    for (int k = 0; k < 4; k++) {
        float p = pr[k];
        float logp = fmaxf(logf(p), -100.0f);
        float log1mp = fmaxf(log1pf(-p), -100.0f);
        acc += (Lg[k] == rv) ? logp : log1mp;
    }
    s[t] = acc;
    __syncthreads();
    for (int st = 128; st > 0; st >>= 1) {
        if (t < st) s[t] += s[t + st];
        __syncthreads();
    }
    if (t == 0) {
        atomicAdd(accum, (double)s[0]);
        __threadfence();
        unsigned int old = atomicAdd(counter, 1u);
        isLast = (old == NCHUNK - 1);
    }
    __syncthreads();
    if (isLast && t == 0) {
        double a = atomicAdd(accum, 0.0);   // coherent read of final total
        out[0] = (float)(-a / (double)NTOT);
    }
}

extern "C" void kernel_launch(void* const* d_in, const int* in_sizes, int n_in,
                              void* d_out, int out_size, void* d_ws, size_t ws_size,
                              hipStream_t stream) {
    const float* pred = (const float*)d_in[0];
    float* out = (float*)d_out;

    char* ws = (char*)d_ws;
    int* L = (int*)ws;                                        // 33.5 MB
    int* P = (int*)(ws + (size_t)NTOT * 4);                   // 33.5 MB
    int* blockSums = (int*)(ws + (size_t)NTOT * 8);           // 32 KB
    int* blockOffs = blockSums + NCHUNK;                      // 32 KB
    unsigned long long* stats =
        (unsigned long long*)(ws + (size_t)NTOT * 8 + (size_t)NCHUNK * 8);
    double* accum = (double*)(stats + NIMG);
    unsigned int* counter = (unsigned int*)(accum + 1);

    dim3 b(256);
    k_local<<<dim3(NTILE), b, 0, stream>>>(pred, L, stats, counter, accum);
    k_border<<<dim3((NBORD + 255) / 256), b, 0, stream>>>(L);
    k_flatten<<<dim3(NCHUNK), b, 0, stream>>>(L, blockSums);
    k_scan<<<dim3(NIMG), b, 0, stream>>>(blockSums, blockOffs);
    k_labels<<<dim3(NCHUNK), b, 0, stream>>>(L, blockOffs, P, stats);
    k_loss<<<dim3(NCHUNK), b, 0, stream>>>(pred, L, P, stats, accum, counter, out);
}

// Round 3
// 205.056 us; speedup vs baseline: 2.7771x; 2.1356x over previous
//
#include <hip/hip_runtime.h>
#include <math.h>

// Problem constants (fixed by reference setup_inputs): pred [32,1,512,512] f32
#define IMG_W 512
#define IMG_H 512
#define HW (IMG_W * IMG_H)      // 262144 = 2^18
#define LOGHW 18
#define NIMG 32
#define NTOT (NIMG * HW)        // 8388608
#define NCHUNK (NTOT / 1024)    // 8192 chunks of 1024 px; 256 per image
#define TILE 64
#define TILES_X (IMG_W / TILE)  // 8
#define TILES_Y (IMG_H / TILE)  // 8
#define TPI (TILES_X * TILES_Y) // 64 tiles per image
#define NTILE (NIMG * TPI)      // 2048
#define VBORD ((TILES_X - 1) * IMG_H)          // 3584 vertical-border pairs/img
#define BORD_PER_IMG (VBORD + (TILES_Y - 1) * IMG_W)  // 7168
#define NBORD (NIMG * BORD_PER_IMG)            // 229376

// ---------------- lock-free min-index union-find ----------------------------
__device__ __forceinline__ int uf_find(const volatile int* L, int x) {
    int p = L[x];
    while (p != x) { x = p; p = L[x]; }
    return x;
}

__device__ __forceinline__ void uf_unite(int* L, int a, int b) {
    while (true) {
        a = uf_find((const volatile int*)L, a);
        b = uf_find((const volatile int*)L, b);
        if (a == b) return;
        if (a < b) { int t = a; a = b; b = t; }  // a > b
        int old = atomicMin(&L[a], b);
        if (old == a) return;
        a = old;
    }
}

// ---------------- K1: fused init + tile-local CCL in LDS --------------------
// One block per 64x64 tile. Local raster order == global raster order within
// a tile, so the LDS union-find's min-local-index root is the min-global-index
// pixel of each tile-portion — exactly what the global UF representation needs.
__global__ __launch_bounds__(256) void k_local(const float* __restrict__ pred,
                                               int* __restrict__ L) {
    __shared__ int lab[TILE * TILE];   // 16 KB
    int tile = blockIdx.x;
    int img = tile >> 6;               // / TPI
    int t = tile & (TPI - 1);
    int ty = t >> 3, tx = t & 7;
    int baseLocal = (ty * TILE) * IMG_W + tx * TILE;  // image-local origin
    const float* pi = pred + ((size_t)img << LOGHW);
    int* Li = L + ((size_t)img << LOGHW);
    int tid = threadIdx.x;

    // load (float4) + init labels
#pragma unroll
    for (int j = 0; j < 4; j++) {
        int i = (tid + j * 256) * 4;              // tile-flat index of 4-pack
        int ly = i >> 6, lx = i & 63;
        const float4 p4 = *(const float4*)(pi + baseLocal + ly * IMG_W + lx);
        lab[i + 0] = (p4.x >= 0.5f) ? i + 0 : -1;
        lab[i + 1] = (p4.y >= 0.5f) ? i + 1 : -1;
        lab[i + 2] = (p4.z >= 0.5f) ? i + 2 : -1;
        lab[i + 3] = (p4.w >= 0.5f) ? i + 3 : -1;
    }
    __syncthreads();
    // local unites (right + down, intra-tile only)
#pragma unroll
    for (int k = 0; k < 16; k++) {
        int i = tid + k * 256;
        if (lab[i] < 0) continue;
        int lx = i & 63;
        if (lx < 63 && lab[i + 1] >= 0) uf_unite(lab, i, i + 1);
        if (i < TILE * TILE - TILE && lab[i + TILE] >= 0) uf_unite(lab, i, i + TILE);
    }
    __syncthreads();
    // flatten + write global parent pointers (int4)
#pragma unroll
    for (int j = 0; j < 4; j++) {
        int i = (tid + j * 256) * 4;
        int ly = i >> 6, lx = i & 63;
        int4 o;
        int* op = (int*)&o;
#pragma unroll
        for (int k = 0; k < 4; k++) {
            int p = lab[i + k];
            if (p < 0) op[k] = -1;
            else {
                int x = i + k;
                while (p != x) { x = p; p = lab[x]; }
                op[k] = baseLocal + (x >> 6) * IMG_W + (x & 63);
            }
        }
        *(int4*)(Li + baseLocal + ly * IMG_W + lx) = o;
    }
}

// ---------------- K2: cross-tile border unites ------------------------------
__global__ void k_border(int* __restrict__ L) {
    int gid = blockIdx.x * blockDim.x + threadIdx.x;
    if (gid >= NBORD) return;
    int img = gid / BORD_PER_IMG;
    int r = gid - img * BORD_PER_IMG;
    int* Li = L + ((size_t)img << LOGHW);
    int a, b;
    if (r < VBORD) {
        int k = r >> 9, y = r & 511;           // r / 512, r % 512
        int x = k * TILE + (TILE - 1);
        a = y * IMG_W + x; b = a + 1;
    } else {
        int r2 = r - VBORD;
        int k = r2 >> 9, x = r2 & 511;
        int y = k * TILE + (TILE - 1);
        a = y * IMG_W + x; b = a + IMG_W;
    }
    if (Li[a] >= 0 && Li[b] >= 0) uf_unite(Li, a, b);
}

// ---------------- K3: flatten to roots + per-chunk root counts --------------
__global__ __launch_bounds__(256) void k_flatten(int* __restrict__ L,
                                                 int* __restrict__ blockSums) {
    __shared__ int sdata[256];
    int base = blockIdx.x * 1024;
    int img = base >> LOGHW;                   // chunks never straddle images
    int* Li = L + ((size_t)img << LOGHW);
    int cnt = 0;
#pragma unroll
    for (int k = 0; k < 4; k++) {
        int g = base + threadIdx.x + k * 256;
        int local = g & (HW - 1);
        int p = Li[local];
        if (p >= 0) {
            int x = local;
            while (p != x) { x = p; p = Li[x]; }
            Li[local] = x;
            cnt += (x == local) ? 1 : 0;
        }
    }
    sdata[threadIdx.x] = cnt;
    __syncthreads();
    for (int s = 128; s > 0; s >>= 1) {
        if (threadIdx.x < s) sdata[threadIdx.x] += sdata[threadIdx.x + s];
        __syncthreads();
    }
    if (threadIdx.x == 0) blockSums[blockIdx.x] = sdata[0];
}

// ---------------- K4: per-image exclusive scan of 256 chunk sums ------------
__global__ void k_scan(const int* __restrict__ blockSums, int* __restrict__ blockOffs) {
    __shared__ int s[256];
    int img = blockIdx.x;
    int t = threadIdx.x;
    int val = blockSums[img * 256 + t];
    s[t] = val;
    __syncthreads();
    for (int off = 1; off < 256; off <<= 1) {
        int v2 = (t >= off) ? s[t - off] : 0;
        __syncthreads();
        s[t] += v2;
        __syncthreads();
    }
    blockOffs[img * 256 + t] = s[t] - val;   // exclusive
}

// ---------------- K5: write inclusive root-prefix P + per-block argmax key --
// Only two pixel classes can win argmax(lf[1:]): a root pixel (it IS the first
// pixel of its component), or a pixel whose root is 0 (label-1 component's
// first index>=1 pixel). Everything else is dominated by its own root's key.
// key = (label << 32) | (HW - index): max label first, min index on ties.
__global__ __launch_bounds__(256) void k_labels(const int* __restrict__ L,
                                                const int* __restrict__ blockOffs,
                                                int* __restrict__ P,
                                                unsigned long long* __restrict__ keys) {
    __shared__ int s[256];
    __shared__ unsigned long long smax[256];
    int base = blockIdx.x * 1024;
    int t = threadIdx.x;
    int4 l4 = *(const int4*)(L + base + t * 4);
    const int* Lg = (const int*)&l4;
    int f[4];
    int sum = 0;
#pragma unroll
    for (int k = 0; k < 4; k++) {
        int local = (base + t * 4 + k) & (HW - 1);
        f[k] = (Lg[k] == local) ? 1 : 0;
        sum += f[k];
    }
    s[t] = sum;
    __syncthreads();
    for (int off = 1; off < 256; off <<= 1) {
        int v2 = (t >= off) ? s[t - off] : 0;
        __syncthreads();
        s[t] += v2;
        __syncthreads();
    }
    int run = (s[t] - sum) + blockOffs[blockIdx.x];
    unsigned long long best = 0ULL;
    int4 p4;
    int* pp = (int*)&p4;
#pragma unroll
    for (int k = 0; k < 4; k++) {
        int local = (base + t * 4 + k) & (HW - 1);
        run += f[k];
        pp[k] = run;
        if (local >= 1) {
            if (f[k]) {
                unsigned long long key =
                    ((unsigned long long)run << 32) | (unsigned)(HW - local);
                if (key > best) best = key;
            }
            if (Lg[k] == 0) {
                unsigned long long key = (1ULL << 32) | (unsigned)(HW - local);
                if (key > best) best = key;
            }
        }
    }
    *(int4*)(P + base + t * 4) = p4;
    smax[t] = best;
    __syncthreads();
    for (int st = 128; st > 0; st >>= 1) {
        if (t < st && smax[t + st] > smax[t]) smax[t] = smax[t + st];
        __syncthreads();
    }
    if (t == 0) keys[blockIdx.x] = smax[0];   // contention-free per-block write
}

// ---------------- K6: per-image key reduce + binary search -> rv[img] -------
// rv[img] = root index whose label equals v (= argmax(lf[1:]) + 1), or -2.
__global__ __launch_bounds__(256) void k_rv(const unsigned long long* __restrict__ keys,
                                            const int* __restrict__ L,
                                            const int* __restrict__ P,
                                            int* __restrict__ rv) {
    __shared__ unsigned long long smax[256];
    int img = blockIdx.x;
    int t = threadIdx.x;
    smax[t] = keys[img * 256 + t];
    __syncthreads();
    for (int st = 128; st > 0; st >>= 1) {
        if (t < st && smax[t + st] > smax[t]) smax[t] = smax[t + st];
        __syncthreads();
    }
    if (t == 0) {
        unsigned long long key = smax[0];
        int v = HW - (int)(key & 0xffffffffULL);   // = argmax(lf[1:]) + 1
        const int* Pi = P + ((size_t)img << LOGHW);
        int r = -2;   // sentinel: never equals any root (-1 = background)
        if (v >= 1 && Pi[HW - 1] >= v) {
            int lo = 0, hi = HW - 1;
            while (lo < hi) {                      // smallest j with Pi[j] >= v
                int mid = (lo + hi) >> 1;
                if (Pi[mid] >= v) hi = mid; else lo = mid + 1;
            }
            if (Pi[lo] == v && L[((size_t)img << LOGHW) + lo] == lo) r = lo;
        }
        rv[img] = r;
    }
}

// ---------------- K7: fused target + clamped BCE, per-block partial ---------
__global__ __launch_bounds__(256) void k_loss(const float* __restrict__ pred,
                                              const int* __restrict__ L,
                                              const int* __restrict__ rvArr,
                                              float* __restrict__ partials) {
    __shared__ float s[256];
    int base = blockIdx.x * 1024;
    int img = base >> LOGHW;
    int t = threadIdx.x;
    int rv = rvArr[img];
    float4 pr4 = *(const float4*)(pred + base + t * 4);
    int4 l4 = *(const int4*)(L + base + t * 4);
    const float* pr = (const float*)&pr4;
    const int* Lg = (const int*)&l4;
    float acc = 0.0f;
#pragma unroll
    for (int k = 0; k < 4; k++) {
        float p = pr[k];
        float logp = fmaxf(logf(p), -100.0f);
        float log1mp = fmaxf(log1pf(-p), -100.0f);
        acc += (Lg[k] == rv) ? logp : log1mp;
    }
    s[t] = acc;
    __syncthreads();
    for (int st = 128; st > 0; st >>= 1) {
        if (t < st) s[t] += s[t + st];
        __syncthreads();
    }
    if (t == 0) partials[blockIdx.x] = s[0];   // contention-free
}

// ---------------- K8: final reduce of 8192 partials -------------------------
__global__ __launch_bounds__(256) void k_final(const float* __restrict__ partials,
                                               float* __restrict__ out) {
    __shared__ double s[256];
    int t = threadIdx.x;
    double acc = 0.0;
#pragma unroll
    for (int j = 0; j < 8; j++) {
        float4 p4 = *(const float4*)(partials + (t + j * 256) * 4);
        acc += (double)p4.x + (double)p4.y + (double)p4.z + (double)p4.w;
    }
    s[t] = acc;
    __syncthreads();
    for (int st = 128; st > 0; st >>= 1) {
        if (t < st) s[t] += s[t + st];
        __syncthreads();
    }
    if (t == 0) out[0] = (float)(-s[0] / (double)NTOT);
}

extern "C" void kernel_launch(void* const* d_in, const int* in_sizes, int n_in,
                              void* d_out, int out_size, void* d_ws, size_t ws_size,
                              hipStream_t stream) {
    const float* pred = (const float*)d_in[0];
    float* out = (float*)d_out;

    char* ws = (char*)d_ws;
    int* L = (int*)ws;                                        // 33.5 MB
    int* P = (int*)(ws + (size_t)NTOT * 4);                   // 33.5 MB
    int* blockSums = (int*)(ws + (size_t)NTOT * 8);           // 32 KB
    int* blockOffs = blockSums + NCHUNK;                      // 32 KB
    unsigned long long* keys =
        (unsigned long long*)(ws + (size_t)NTOT * 8 + (size_t)NCHUNK * 8);  // 64 KB
    float* partials = (float*)(keys + NCHUNK);                // 32 KB
    int* rv = (int*)(partials + NCHUNK);                      // 128 B

    dim3 b(256);
    k_local<<<dim3(NTILE), b, 0, stream>>>(pred, L);
    k_border<<<dim3((NBORD + 255) / 256), b, 0, stream>>>(L);
    k_flatten<<<dim3(NCHUNK), b, 0, stream>>>(L, blockSums);
    k_scan<<<dim3(NIMG), b, 0, stream>>>(blockSums, blockOffs);
    k_labels<<<dim3(NCHUNK), b, 0, stream>>>(L, blockOffs, P, keys);
    k_rv<<<dim3(NIMG), b, 0, stream>>>(keys, L, P, rv);
    k_loss<<<dim3(NCHUNK), b, 0, stream>>>(pred, L, rv, partials);
    k_final<<<1, b, 0, stream>>>(partials, out);
}

// Round 4
// 134.137 us; speedup vs baseline: 4.2454x; 1.5287x over previous
//
#include <hip/hip_runtime.h>
#include <math.h>

// Problem constants (fixed by reference setup_inputs): pred [32,1,512,512] f32
#define IMG_W 512
#define IMG_H 512
#define HW (IMG_W * IMG_H)      // 262144 = 2^18
#define LOGHW 18
#define NIMG 32
#define NTOT (NIMG * HW)        // 8388608
#define TILE 64
#define TPI 64                  // 8x8 tiles of 64x64 per image
#define NTILE (NIMG * TPI)      // 2048
#define CPI 64                  // stat-chunks per image (4096 px each)
#define NSCHUNK (NIMG * CPI)    // 2048
#define VBORD ((8 - 1) * IMG_H)                 // 3584 vertical-border pairs/img
#define BORD_PER_IMG (VBORD + (8 - 1) * IMG_W)  // 7168
#define NBORD (NIMG * BORD_PER_IMG)             // 229376

// ---------------- lock-free min-index union-find ----------------------------
__device__ __forceinline__ void uf_unite(int* L, int a, int b) {
    while (true) {
        // find roots (reads may be stale -> only costs retries, never wrong)
        int p = ((volatile int*)L)[a];
        while (p != a) { a = p; p = ((volatile int*)L)[a]; }
        p = ((volatile int*)L)[b];
        while (p != b) { b = p; p = ((volatile int*)L)[b]; }
        if (a == b) return;
        if (a < b) { int t = a; a = b; b = t; }  // a > b
        int old = atomicMin(&L[a], b);
        if (old == a) return;
        a = old;
    }
}

// ---------------- K1: ballot row-run CCL + vertical unites + base BCE -------
// One block per 64x64 tile; tile row width == wave width (64). Row runs are
// labeled in O(1) via ballot (run start = min index of run). Only vertical
// run-pair contacts go through the LDS union-find. Local raster order ==
// global raster order within a tile, so min-index roots are exact.
// Also accumulates the target-independent BCE term sum(log1p(-p)) since pred
// is already in registers.
__global__ __launch_bounds__(256) void k_local(const float* __restrict__ pred,
                                               int* __restrict__ L,
                                               float* __restrict__ partials) {
    __shared__ int lab[TILE * TILE];   // 16 KB
    __shared__ float sred[256];
    int tile = blockIdx.x;
    int img = tile >> 6;
    int t = tile & (TPI - 1);
    int ty = t >> 3, tx = t & 7;
    int baseLocal = (ty * TILE) * IMG_W + tx * TILE;  // image-local origin
    const float* pi = pred + ((size_t)img << LOGHW);
    int* Li = L + ((size_t)img << LOGHW);
    int tid = threadIdx.x;
    int lane = tid & 63, wave = tid >> 6;

    float acc = 0.0f;
    // ---- pass 1: row-run labels via ballot (wave w handles rows r%4==w) ----
#pragma unroll
    for (int j = 0; j < 16; j++) {
        int row = wave + j * 4;
        float p = pi[baseLocal + row * IMG_W + lane];
        acc += fmaxf(log1pf(-p), -100.0f);
        bool fg = (p >= 0.5f);
        unsigned long long bal = __ballot(fg);
        unsigned long long starts = bal & ~(bal << 1);
        unsigned long long maskle =
            (lane == 63) ? ~0ULL : ((1ULL << (lane + 1)) - 1ULL);
        int lb = -1;
        if (fg) {
            unsigned long long pre = starts & maskle;   // nonzero when fg
            int startLane = 63 - __builtin_clzll(pre);
            lb = row * TILE + startLane;
        }
        lab[row * TILE + lane] = lb;
    }
    __syncthreads();
    // ---- pass 2: vertical unites, one per contact-run ----------------------
#pragma unroll
    for (int j = 0; j < 16; j++) {
        int row = 1 + wave + j * 4;
        if (row > 63) break;                      // wave-uniform
        int i = row * TILE + lane;
        bool c = (lab[i] >= 0) && (lab[i - TILE] >= 0);
        unsigned long long cb = __ballot(c);
        unsigned long long cs = cb & ~(cb << 1);  // first lane of each contact
        if ((cs >> lane) & 1ULL) uf_unite(lab, i, i - TILE);
    }
    __syncthreads();
    // ---- pass 3: flatten + write image-local root pointers (int4) ----------
#pragma unroll
    for (int j = 0; j < 4; j++) {
        int i4 = (tid + j * 256) * 4;
        int ly = i4 >> 6, lx = i4 & 63;
        int4 o;
        int* op = (int*)&o;
#pragma unroll
        for (int k = 0; k < 4; k++) {
            int p = lab[i4 + k];
            if (p < 0) op[k] = -1;
            else {
                int x = i4 + k;
                while (p != x) { x = p; p = lab[x]; }
                op[k] = baseLocal + (x >> 6) * IMG_W + (x & 63);
            }
        }
        *(int4*)(Li + baseLocal + ly * IMG_W + lx) = o;
    }
    // ---- base BCE block reduce ---------------------------------------------
    sred[tid] = acc;
    __syncthreads();
    for (int s = 128; s > 0; s >>= 1) {
        if (tid < s) sred[tid] += sred[tid + s];
        __syncthreads();
    }
    if (tid == 0) partials[blockIdx.x] = sred[0];
}

// ---------------- K2: cross-tile border unites ------------------------------
__global__ void k_border(int* __restrict__ L) {
    int gid = blockIdx.x * blockDim.x + threadIdx.x;
    if (gid >= NBORD) return;
    int img = gid / BORD_PER_IMG;
    int r = gid - img * BORD_PER_IMG;
    int* Li = L + ((size_t)img << LOGHW);
    int a, b;
    if (r < VBORD) {
        int k = r >> 9, y = r & 511;
        int x = k * TILE + (TILE - 1);
        a = y * IMG_W + x; b = a + 1;
    } else {
        int r2 = r - VBORD;
        int k = r2 >> 9, x = r2 & 511;
        int y = k * TILE + (TILE - 1);
        a = y * IMG_W + x; b = a + IMG_W;
    }
    if (Li[a] >= 0 && Li[b] >= 0) uf_unite(Li, a, b);
}

// ---------------- K3: per-chunk stats (4096 px): roots, maxRoot, minFg ------
// Root flags (L[i]==i) are invariant under path compression, so no chasing
// and no writeback needed here.
__global__ __launch_bounds__(256) void k_stats(const int* __restrict__ L,
                                               int* __restrict__ cntArr,
                                               int* __restrict__ maxArr,
                                               int* __restrict__ minArr) {
    __shared__ int s1[256], s2[256], s3[256];
    int chunk = blockIdx.x;
    int img = chunk >> 6;
    int baseL = (chunk & 63) * 4096;             // image-local
    const int* Li = L + ((size_t)img << LOGHW);
    int t = threadIdx.x;
    int cnt = 0, mx = -1, mn = HW;
#pragma unroll
    for (int j = 0; j < 4; j++) {
        int off = baseL + (t + j * 256) * 4;
        int4 l4 = *(const int4*)(Li + off);
        const int* lp = (const int*)&l4;
#pragma unroll
        for (int k = 0; k < 4; k++) {
            int local = off + k;
            int p = lp[k];
            bool root = (p == local);
            cnt += root ? 1 : 0;
            if (root && local > mx) mx = local;
            if (p >= 0 && local >= 1 && local < mn) mn = local;
        }
    }
    s1[t] = cnt; s2[t] = mx; s3[t] = mn;
    __syncthreads();
    for (int s = 128; s > 0; s >>= 1) {
        if (t < s) {
            s1[t] += s1[t + s];
            s2[t] = max(s2[t], s2[t + s]);
            s3[t] = min(s3[t], s3[t + s]);
        }
        __syncthreads();
    }
    if (t == 0) { cntArr[chunk] = s1[0]; maxArr[chunk] = s2[0]; minArr[chunk] = s3[0]; }
}

// ---------------- K4: per-image v + select v-th root -> rv[img] -------------
// v = argmax(lf[1:]) + 1 equals: index of LAST root (if >=1); else (single
// component rooted at 0) the first fg index >=1, or 1 if none; else 1.
// rv = v-th root in raster order if 1<=v<=num, else -2 (target empty).
__global__ __launch_bounds__(256) void k_rv(const int* __restrict__ cntArr,
                                            const int* __restrict__ maxArr,
                                            const int* __restrict__ minArr,
                                            const int* __restrict__ L,
                                            int* __restrict__ rv) {
    __shared__ int sc[256], sm[256], sn[256];
    __shared__ int sel_chunk, sel_base, result;
    int img = blockIdx.x, t = threadIdx.x;
    int cnt = (t < CPI) ? cntArr[img * CPI + t] : 0;
    sc[t] = cnt;
    sm[t] = (t < CPI) ? maxArr[img * CPI + t] : -1;
    sn[t] = (t < CPI) ? minArr[img * CPI + t] : HW;
    if (t == 0) result = -2;
    __syncthreads();
    // inclusive scan of counts
    for (int off = 1; off < 256; off <<= 1) {
        int v2 = (t >= off) ? sc[t - off] : 0;
        __syncthreads();
        sc[t] += v2;
        __syncthreads();
    }
    int num = sc[255];
    int inc = sc[t], exc = inc - cnt;
    // max/min reduce (syncs also fence the num/inc/exc reads above)
    for (int s = 128; s > 0; s >>= 1) {
        if (t < s) { sm[t] = max(sm[t], sm[t + s]); sn[t] = min(sn[t], sn[t + s]); }
        __syncthreads();
    }
    int last_root = sm[0], minFg = sn[0];
    int v;
    if (last_root >= 1) v = last_root;
    else if (last_root == 0) v = (minFg < HW) ? minFg : 1;
    else v = 1;
    if (v >= 1 && v <= num) {            // block-uniform branch
        if (exc < v && v <= inc) { sel_chunk = t; sel_base = exc; }
        __syncthreads();
        int c = sel_chunk, base = sel_base;
        const int* Li = L + ((size_t)img << LOGHW);
        int baseL = c * 4096;
        int f[16];
        int sum = 0;
#pragma unroll
        for (int j = 0; j < 4; j++) {
            int off = baseL + t * 16 + j * 4;
            int4 l4 = *(const int4*)(Li + off);
            const int* lp = (const int*)&l4;
#pragma unroll
            for (int k = 0; k < 4; k++) {
                f[j * 4 + k] = (lp[k] == off + k) ? 1 : 0;
                sum += f[j * 4 + k];
            }
        }
        __syncthreads();                  // done reading sc from scan 1
        sc[t] = sum;
        __syncthreads();
        for (int off = 1; off < 256; off <<= 1) {
            int v2 = (t >= off) ? sc[t - off] : 0;
            __syncthreads();
            sc[t] += v2;
            __syncthreads();
        }
        int exc2 = sc[t] - sum;
        int need = v - base;
        if (exc2 < need && need <= sc[t]) {
            int run = exc2;
#pragma unroll
            for (int k = 0; k < 16; k++) {
                run += f[k];
                if (run == need) { result = baseL + t * 16 + k; break; }
            }
        }
        __syncthreads();
    } else {
        __syncthreads();
    }
    if (t == 0) rv[img] = result;
}

// ---------------- K5: correction term sum_{root==rv}(logp - log1mp) --------
// rv is -2 (target empty) for typical random inputs -> near-instant exit.
__global__ __launch_bounds__(256) void k_loss(const float* __restrict__ pred,
                                              const int* __restrict__ L,
                                              const int* __restrict__ rvArr,
                                              float* __restrict__ partials2) {
    __shared__ float sred[256];
    int blk = blockIdx.x;                // 2048 blocks x 4096 px
    int img = blk >> 6;
    int rvv = rvArr[img];
    if (rvv < 0) {
        if (threadIdx.x == 0) partials2[blk] = 0.0f;
        return;
    }
    const int* Li = L + ((size_t)img << LOGHW);
    int baseG = blk * 4096;
    int t = threadIdx.x;
    float acc = 0.0f;
#pragma unroll
    for (int j = 0; j < 4; j++) {
        int off = baseG + (t + j * 256) * 4;
        float4 p4 = *(const float4*)(pred + off);
        int4 l4 = *(const int4*)(L + off);
        const float* pp = (const float*)&p4;
        const int* lp = (const int*)&l4;
#pragma unroll
        for (int k = 0; k < 4; k++) {
            int p = lp[k];
            if (p < 0) continue;
            int x = p;
            int q = Li[x];
            while (q != x) { x = q; q = Li[x]; }   // chase to root
            if (x == rvv) {
                float pr = pp[k];
                float logp = fmaxf(logf(pr), -100.0f);
                float log1mp = fmaxf(log1pf(-pr), -100.0f);
                acc += logp - log1mp;
            }
        }
    }
    sred[t] = acc;
    __syncthreads();
    for (int s = 128; s > 0; s >>= 1) {
        if (t < s) sred[t] += sred[t + s];
        __syncthreads();
    }
    if (t == 0) partials2[blk] = sred[0];
}

// ---------------- K6: final reduce ------------------------------------------
__global__ __launch_bounds__(256) void k_final(const float* __restrict__ partials,
                                               const float* __restrict__ partials2,
                                               float* __restrict__ out) {
    __shared__ double s[256];
    int t = threadIdx.x;
    double acc = 0.0;
#pragma unroll
    for (int j = 0; j < 8; j++) {
        acc += (double)partials[t + j * 256] + (double)partials2[t + j * 256];
    }
    s[t] = acc;
    __syncthreads();
    for (int st = 128; st > 0; st >>= 1) {
        if (t < st) s[t] += s[t + st];
        __syncthreads();
    }
    if (t == 0) out[0] = (float)(-s[0] / (double)NTOT);
}

extern "C" void kernel_launch(void* const* d_in, const int* in_sizes, int n_in,
                              void* d_out, int out_size, void* d_ws, size_t ws_size,
                              hipStream_t stream) {
    const float* pred = (const float*)d_in[0];
    float* out = (float*)d_out;

    char* ws = (char*)d_ws;
    int* L = (int*)ws;                                        // 33.5 MB
    int* cntArr = (int*)(ws + (size_t)NTOT * 4);              // 8 KB
    int* maxArr = cntArr + NSCHUNK;                           // 8 KB
    int* minArr = maxArr + NSCHUNK;                           // 8 KB
    float* partials = (float*)(minArr + NSCHUNK);             // 8 KB
    float* partials2 = partials + NTILE;                      // 8 KB
    int* rv = (int*)(partials2 + NTILE);                      // 128 B

    dim3 b(256);
    k_local<<<dim3(NTILE), b, 0, stream>>>(pred, L, partials);
    k_border<<<dim3((NBORD + 255) / 256), b, 0, stream>>>(L);
    k_stats<<<dim3(NSCHUNK), b, 0, stream>>>(L, cntArr, maxArr, minArr);
    k_rv<<<dim3(NIMG), b, 0, stream>>>(cntArr, maxArr, minArr, L, rv);
    k_loss<<<dim3(NTILE), b, 0, stream>>>(pred, L, rv, partials2);
    k_final<<<1, b, 0, stream>>>(partials, partials2, out);
}

// Round 5
// 124.525 us; speedup vs baseline: 4.5730x; 1.0772x over previous
//
#include <hip/hip_runtime.h>
#include <math.h>

// Problem constants (fixed by reference setup_inputs): pred [32,1,512,512] f32
#define IMG_W 512
#define IMG_H 512
#define HW (IMG_W * IMG_H)      // 262144 = 2^18
#define LOGHW 18
#define NIMG 32
#define NTOT (NIMG * HW)        // 8388608
#define TILE 64
#define TPI 64                  // 8x8 tiles of 64x64 per image
#define NTILE (NIMG * TPI)      // 2048
#define CPI 64                  // stat-chunks per image (4096 px each)
#define NSCHUNK (NIMG * CPI)    // 2048
#define VBORD ((8 - 1) * IMG_H)                 // 3584 vertical-border pairs/img
#define BORD_PER_IMG (VBORD + (8 - 1) * IMG_W)  // 7168
#define NBORD (NIMG * BORD_PER_IMG)             // 229376

// ---------------- lock-free min-index union-find ----------------------------
__device__ __forceinline__ void uf_unite(int* L, int a, int b) {
    while (true) {
        // find roots (reads may be stale -> only costs retries, never wrong)
        int p = ((volatile int*)L)[a];
        while (p != a) { a = p; p = ((volatile int*)L)[a]; }
        p = ((volatile int*)L)[b];
        while (p != b) { b = p; p = ((volatile int*)L)[b]; }
        if (a == b) return;
        if (a < b) { int t = a; a = b; b = t; }  // a > b
        int old = atomicMin(&L[a], b);
        if (old == a) return;
        a = old;
    }
}

// ---------------- K1: pure CCL: ballot row-runs + vertical unites -----------
// One block per 64x64 tile; tile row width == wave width (64). Row runs are
// labeled in O(1) via ballot (run start = min index of run). Only vertical
// run-pair contacts go through the LDS union-find (~750/tile). Local raster
// order == global raster order within a tile, so min-index roots are exact.
// NO transcendental math here (it moved to k_loss) — this kernel was
// VALU-bound on ocml log1pf in R4.
__global__ __launch_bounds__(256) void k_local(const float* __restrict__ pred,
                                               int* __restrict__ L) {
    __shared__ int lab[TILE * TILE];   // 16 KB
    int tile = blockIdx.x;
    int img = tile >> 6;
    int t = tile & (TPI - 1);
    int ty = t >> 3, tx = t & 7;
    int baseLocal = (ty * TILE) * IMG_W + tx * TILE;  // image-local origin
    const float* pi = pred + ((size_t)img << LOGHW);
    int* Li = L + ((size_t)img << LOGHW);
    int tid = threadIdx.x;
    int lane = tid & 63, wave = tid >> 6;

    // ---- pass 1: row-run labels via ballot (wave w handles rows r%4==w) ----
#pragma unroll
    for (int j = 0; j < 16; j++) {
        int row = wave + j * 4;
        float p = pi[baseLocal + row * IMG_W + lane];
        bool fg = (p >= 0.5f);
        unsigned long long bal = __ballot(fg);
        unsigned long long starts = bal & ~(bal << 1);
        unsigned long long maskle =
            (lane == 63) ? ~0ULL : ((1ULL << (lane + 1)) - 1ULL);
        int lb = -1;
        if (fg) {
            unsigned long long pre = starts & maskle;   // nonzero when fg
            int startLane = 63 - __builtin_clzll(pre);
            lb = row * TILE + startLane;
        }
        lab[row * TILE + lane] = lb;
    }
    __syncthreads();
    // ---- pass 2: vertical unites, one per contact-run ----------------------
#pragma unroll
    for (int j = 0; j < 16; j++) {
        int row = 1 + wave + j * 4;
        if (row > 63) break;                      // wave-uniform
        int i = row * TILE + lane;
        bool c = (lab[i] >= 0) && (lab[i - TILE] >= 0);
        unsigned long long cb = __ballot(c);
        unsigned long long cs = cb & ~(cb << 1);  // first lane of each contact
        if ((cs >> lane) & 1ULL) uf_unite(lab, i, i - TILE);
    }
    __syncthreads();
    // ---- pass 3: flatten (path halving) + write image-local roots (int4) ---
#pragma unroll
    for (int j = 0; j < 4; j++) {
        int i4 = (tid + j * 256) * 4;
        int ly = i4 >> 6, lx = i4 & 63;
        int4 o;
        int* op = (int*)&o;
#pragma unroll
        for (int k = 0; k < 4; k++) {
            int x = i4 + k;
            int p = lab[x];
            if (p < 0) op[k] = -1;
            else {
                while (p != x) {
                    int g = lab[p];     // grandparent (or parent if p is root)
                    lab[x] = g;         // path halving: benign race, ancestors only
                    x = g;
                    p = lab[x];
                }
                op[k] = baseLocal + (x >> 6) * IMG_W + (x & 63);
            }
        }
        *(int4*)(Li + baseLocal + ly * IMG_W + lx) = o;
    }
}

// ---------------- K2: cross-tile border unites, ballot-compressed -----------
// Consecutive contact pairs along an edge are redundant: the edge-parallel
// neighbors are already united inside their tiles. Unite only at contact-run
// starts (lane 0 always unites on contact: at most 1 redundant unite/wave).
// Waves never straddle edges: 512, VBORD, BORD_PER_IMG all multiples of 64.
__global__ void k_border(int* __restrict__ L) {
    int gid = blockIdx.x * blockDim.x + threadIdx.x;
    int img = gid / BORD_PER_IMG;                // wave-uniform
    int r = gid - img * BORD_PER_IMG;
    int* Li = L + ((size_t)img << LOGHW);
    int a, b;
    if (r < VBORD) {                             // wave-uniform branch
        int k = r >> 9, y = r & 511;
        int x = k * TILE + (TILE - 1);
        a = y * IMG_W + x; b = a + 1;
    } else {
        int r2 = r - VBORD;
        int k = r2 >> 9, x = r2 & 511;
        int y = k * TILE + (TILE - 1);
        a = y * IMG_W + x; b = a + IMG_W;
    }
    bool c = (Li[a] >= 0) && (Li[b] >= 0);
    unsigned long long cb = __ballot(c);
    unsigned long long cs = cb & ~(cb << 1);     // contact-run starts
    if ((cs >> (threadIdx.x & 63)) & 1ULL) uf_unite(Li, a, b);
}

// ---------------- K3: per-chunk stats (4096 px): roots, maxRoot, minFg ------
// Root flags (L[i]==i) are invariant under path compression: no chase needed.
__global__ __launch_bounds__(256) void k_stats(const int* __restrict__ L,
                                               int* __restrict__ cntArr,
                                               int* __restrict__ maxArr,
                                               int* __restrict__ minArr) {
    __shared__ int s1[256], s2[256], s3[256];
    int chunk = blockIdx.x;
    int img = chunk >> 6;
    int baseL = (chunk & 63) * 4096;             // image-local
    const int* Li = L + ((size_t)img << LOGHW);
    int t = threadIdx.x;
    int cnt = 0, mx = -1, mn = HW;
#pragma unroll
    for (int j = 0; j < 4; j++) {
        int off = baseL + (t + j * 256) * 4;
        int4 l4 = *(const int4*)(Li + off);
        const int* lp = (const int*)&l4;
#pragma unroll
        for (int k = 0; k < 4; k++) {
            int local = off + k;
            int p = lp[k];
            bool root = (p == local);
            cnt += root ? 1 : 0;
            if (root && local > mx) mx = local;
            if (p >= 0 && local >= 1 && local < mn) mn = local;
        }
    }
    s1[t] = cnt; s2[t] = mx; s3[t] = mn;
    __syncthreads();
    for (int s = 128; s > 0; s >>= 1) {
        if (t < s) {
            s1[t] += s1[t + s];
            s2[t] = max(s2[t], s2[t + s]);
            s3[t] = min(s3[t], s3[t + s]);
        }
        __syncthreads();
    }
    if (t == 0) { cntArr[chunk] = s1[0]; maxArr[chunk] = s2[0]; minArr[chunk] = s3[0]; }
}

// ---------------- K4: per-image v + select v-th root -> rv[img] -------------
// v = argmax(lf[1:]) + 1 equals: index of LAST root (if >=1); else (single
// component rooted at 0) the first fg index >=1, or 1 if none; else 1.
// rv = v-th root in raster order if 1<=v<=num, else -2 (target empty).
__global__ __launch_bounds__(256) void k_rv(const int* __restrict__ cntArr,
                                            const int* __restrict__ maxArr,
                                            const int* __restrict__ minArr,
                                            const int* __restrict__ L,
                                            int* __restrict__ rv) {
    __shared__ int sc[256], sm[256], sn[256];
    __shared__ int sel_chunk, sel_base, result;
    int img = blockIdx.x, t = threadIdx.x;
    int cnt = (t < CPI) ? cntArr[img * CPI + t] : 0;
    sc[t] = cnt;
    sm[t] = (t < CPI) ? maxArr[img * CPI + t] : -1;
    sn[t] = (t < CPI) ? minArr[img * CPI + t] : HW;
    if (t == 0) result = -2;
    __syncthreads();
    // inclusive scan of counts
    for (int off = 1; off < 256; off <<= 1) {
        int v2 = (t >= off) ? sc[t - off] : 0;
        __syncthreads();
        sc[t] += v2;
        __syncthreads();
    }
    int num = sc[255];
    int inc = sc[t], exc = inc - cnt;
    // max/min reduce (syncs also fence the num/inc/exc reads above)
    for (int s = 128; s > 0; s >>= 1) {
        if (t < s) { sm[t] = max(sm[t], sm[t + s]); sn[t] = min(sn[t], sn[t + s]); }
        __syncthreads();
    }
    int last_root = sm[0], minFg = sn[0];
    int v;
    if (last_root >= 1) v = last_root;
    else if (last_root == 0) v = (minFg < HW) ? minFg : 1;
    else v = 1;
    if (v >= 1 && v <= num) {            // block-uniform branch
        if (exc < v && v <= inc) { sel_chunk = t; sel_base = exc; }
        __syncthreads();
        int c = sel_chunk, base = sel_base;
        const int* Li = L + ((size_t)img << LOGHW);
        int baseL = c * 4096;
        int f[16];
        int sum = 0;
#pragma unroll
        for (int j = 0; j < 4; j++) {
            int off = baseL + t * 16 + j * 4;
            int4 l4 = *(const int4*)(Li + off);
            const int* lp = (const int*)&l4;
#pragma unroll
            for (int k = 0; k < 4; k++) {
                f[j * 4 + k] = (lp[k] == off + k) ? 1 : 0;
                sum += f[j * 4 + k];
            }
        }
        __syncthreads();                  // done reading sc from scan 1
        sc[t] = sum;
        __syncthreads();
        for (int off = 1; off < 256; off <<= 1) {
            int v2 = (t >= off) ? sc[t - off] : 0;
            __syncthreads();
            sc[t] += v2;
            __syncthreads();
        }
        int exc2 = sc[t] - sum;
        int need = v - base;
        if (exc2 < need && need <= sc[t]) {
            int run = exc2;
#pragma unroll
            for (int k = 0; k < 16; k++) {
                run += f[k];
                if (run == need) { result = baseL + t * 16 + k; break; }
            }
        }
        __syncthreads();
    } else {
        __syncthreads();
    }
    if (t == 0) rv[img] = result;
}

// ---------------- K5: fused BCE (base + correction), per-block partial ------
// base = sum fmax(log(1-p), -100) over all px; correction adds
// (logp - log1mp) for px in the rv component. rv = -2 (empty target) is the
// common case for random input -> pure streaming over pred only.
// __logf: v_log_f32 native; 1-p exact for p>=0.5 (Sterbenz), <=1ulp otherwise.
__global__ __launch_bounds__(256) void k_loss(const float* __restrict__ pred,
                                              const int* __restrict__ L,
                                              const int* __restrict__ rvArr,
                                              float* __restrict__ partials) {
    __shared__ float sred[256];
    int blk = blockIdx.x;                // 2048 blocks x 4096 px
    int img = blk >> 6;
    int rvv = rvArr[img];
    int baseG = blk * 4096;
    int t = threadIdx.x;
    float acc = 0.0f;
    if (rvv < 0) {                       // block-uniform
#pragma unroll
        for (int j = 0; j < 4; j++) {
            int off = baseG + (t + j * 256) * 4;
            float4 p4 = *(const float4*)(pred + off);
            const float* pp = (const float*)&p4;
#pragma unroll
            for (int k = 0; k < 4; k++)
                acc += fmaxf(__logf(1.0f - pp[k]), -100.0f);
        }
    } else {
        const int* Li = L + ((size_t)img << LOGHW);
#pragma unroll
        for (int j = 0; j < 4; j++) {
            int off = baseG + (t + j * 256) * 4;
            float4 p4 = *(const float4*)(pred + off);
            int4 l4 = *(const int4*)(L + off);
            const float* pp = (const float*)&p4;
            const int* lp = (const int*)&l4;
#pragma unroll
            for (int k = 0; k < 4; k++) {
                float pr = pp[k];
                float log1mp = fmaxf(__logf(1.0f - pr), -100.0f);
                acc += log1mp;
                int p = lp[k];
                if (p >= 0) {
                    int x = p, q = Li[x];
                    while (q != x) { x = q; q = Li[x]; }   // chase to root
                    if (x == rvv)
                        acc += fmaxf(__logf(pr), -100.0f) - log1mp;
                }
            }
        }
    }
    sred[t] = acc;
    __syncthreads();
    for (int s = 128; s > 0; s >>= 1) {
        if (t < s) sred[t] += sred[t + s];
        __syncthreads();
    }
    if (t == 0) partials[blk] = sred[0];
}

// ---------------- K6: final reduce ------------------------------------------
__global__ __launch_bounds__(256) void k_final(const float* __restrict__ partials,
                                               float* __restrict__ out) {
    __shared__ double s[256];
    int t = threadIdx.x;
    double acc = 0.0;
#pragma unroll
    for (int j = 0; j < 8; j++) acc += (double)partials[t + j * 256];
    s[t] = acc;
    __syncthreads();
    for (int st = 128; st > 0; st >>= 1) {
        if (t < st) s[t] += s[t + st];
        __syncthreads();
    }
    if (t == 0) out[0] = (float)(-s[0] / (double)NTOT);
}

extern "C" void kernel_launch(void* const* d_in, const int* in_sizes, int n_in,
                              void* d_out, int out_size, void* d_ws, size_t ws_size,
                              hipStream_t stream) {
    const float* pred = (const float*)d_in[0];
    float* out = (float*)d_out;

    char* ws = (char*)d_ws;
    int* L = (int*)ws;                                        // 33.5 MB
    int* cntArr = (int*)(ws + (size_t)NTOT * 4);              // 8 KB
    int* maxArr = cntArr + NSCHUNK;                           // 8 KB
    int* minArr = maxArr + NSCHUNK;                           // 8 KB
    float* partials = (float*)(minArr + NSCHUNK);             // 8 KB
    int* rv = (int*)(partials + NSCHUNK);                     // 128 B

    dim3 b(256);
    k_local<<<dim3(NTILE), b, 0, stream>>>(pred, L);
    k_border<<<dim3(NBORD / 256), b, 0, stream>>>(L);
    k_stats<<<dim3(NSCHUNK), b, 0, stream>>>(L, cntArr, maxArr, minArr);
    k_rv<<<dim3(NIMG), b, 0, stream>>>(cntArr, maxArr, minArr, L, rv);
    k_loss<<<dim3(NSCHUNK), b, 0, stream>>>(pred, L, rv, partials);
    k_final<<<1, b, 0, stream>>>(partials, out);
}